// Round 10
// baseline (259.063 us; speedup 1.0000x reference)
//
#include <hip/hip_runtime.h>
#include <hip/hip_bf16.h>

// Problem: B=2, S=2048, H=1024, HEADS=16, HEAD_DIM=64. Wire dtype fp32; output fp32.
// R10: (a) attn: PV via K=16 MFMA consuming softmax output DIRECTLY from
// registers (S^T C-layout == 16x16x16 B-layout) -> P LDS roundtrip deleted;
// mask folded into precomputed exp2 addend in LDS (removes per-iter VMEM+VALU).
// (b) qkv/oproj: BK=64 per barrier-pair (two 128x32 m97 sub-tiles) -> half the
// barrier drains. Epilogues unchanged from R9.
#define SEQ     2048
#define BATCH   2
#define HID     1024
#define NHEADS  16
#define HD      64
#define MTOT    4096            // BATCH*SEQ
#define LNEPS   1e-6f
#define L2E     1.4426950408889634f
#define SHIFT2  26.0f           // base-2 static softmax shift

typedef __bf16 bf16_t;
typedef bf16_t bf16x8 __attribute__((ext_vector_type(8)));   // 4 VGPRs = K=32 MFMA A/B frag
typedef bf16_t bf16x4 __attribute__((ext_vector_type(4)));   // 2 VGPRs = K=16 MFMA A/B frag
typedef short  short4v __attribute__((ext_vector_type(4)));
typedef float  floatx4 __attribute__((ext_vector_type(4)));  // MFMA C/D frag

__device__ __forceinline__ floatx4 mfma16(bf16x8 a, bf16x8 b, floatx4 c) {
    return __builtin_amdgcn_mfma_f32_16x16x32_bf16(a, b, c, 0, 0, 0);
}
// K=16 bf16 MFMA (v_mfma_f32_16x16x16_bf16, 2-reg operands)
__device__ __forceinline__ floatx4 mfma16k16(bf16x4 a, bf16x4 b, floatx4 c) {
    short4v as = __builtin_bit_cast(short4v, a);
    short4v bs = __builtin_bit_cast(short4v, b);
    return __builtin_amdgcn_mfma_f32_16x16x16bf16_1k(as, bs, c, 0, 0, 0);
}
__device__ __forceinline__ bf16x8 ldg8(const bf16_t* p) { return *(const bf16x8*)p; }

// Stage one 128x32 bf16 tile (rows [0,128), cols [k0,k0+32), row-major,
// row_stride elems) into LDS via global_load_lds width 16.
__device__ __forceinline__ void stage128x32(const bf16_t* __restrict__ g, int row_stride,
                                            int k0, bf16_t* lds, int wave, int lane)
{
#pragma unroll
    for (int j = 0; j < 2; j++) {
        const int rbase = wave * 32 + j * 16;
        const bf16_t* src = g + (size_t)(rbase + (lane >> 2)) * row_stride + k0 + (lane & 3) * 8;
        bf16_t* dst = lds + rbase * 32;
        __builtin_amdgcn_global_load_lds(
            (const __attribute__((address_space(1))) unsigned int*)src,
            (__attribute__((address_space(3))) unsigned int*)dst, 16, 0, 0);
    }
}

// ---------------------------------------------------------------------------
// Kernel 0: fp32 -> bf16 conversion for X, Wq, Wk, Wv, Wo.
// ---------------------------------------------------------------------------
__global__ __launch_bounds__(256) void cvt_kernel(
    const float* sX, const float* sWq, const float* sWk, const float* sWv, const float* sWo,
    bf16_t* dX, bf16_t* dWq, bf16_t* dWk, bf16_t* dWv, bf16_t* dWo)
{
    const int z = blockIdx.z;
    const float* src; bf16_t* dst; int n;
    switch (z) {
        case 0:  src = sX;  dst = dX;  n = MTOT * HID; break;
        case 1:  src = sWq; dst = dWq; n = HID * HID;  break;
        case 2:  src = sWk; dst = dWk; n = HID * HID;  break;
        case 3:  src = sWv; dst = dWv; n = HID * HID;  break;
        default: src = sWo; dst = dWo; n = HID * HID;  break;
    }
    const int n4 = n >> 2;
    const int stride = gridDim.x * blockDim.x;
    for (int i = blockIdx.x * blockDim.x + threadIdx.x; i < n4; i += stride) {
        const float4 v = ((const float4*)src)[i];
        bf16_t o[4] = {(bf16_t)v.x, (bf16_t)v.y, (bf16_t)v.z, (bf16_t)v.w};
        *(unsigned long long*)(dst + 4 * i) = *(unsigned long long*)o;
    }
}

// ---------------------------------------------------------------------------
// Kernel 1: QKV projection (NT GEMM). BK=64 per barrier-pair (2 sub-tiles).
// Q pre-scaled by 0.125. Q,K stored [bh][s][d] (LDS-transposed stores);
// V stored TRANSPOSED [bh][d][s] (packed b64).
// ---------------------------------------------------------------------------
__global__ __launch_bounds__(256) void qkv_kernel(
    const bf16_t* __restrict__ X,
    const bf16_t* __restrict__ Wq, const float* __restrict__ bq,
    const bf16_t* __restrict__ Wk, const float* __restrict__ bk,
    const bf16_t* __restrict__ Wv, const float* __restrict__ bv,
    bf16_t* __restrict__ Qo, bf16_t* __restrict__ Ko, bf16_t* __restrict__ Vo)
{
    const int z = blockIdx.z;
    const bf16_t* W    = (z == 0) ? Wq : (z == 1) ? Wk : Wv;
    const float*  bias = (z == 0) ? bq : (z == 1) ? bk : bv;
    bf16_t*       out  = (z == 0) ? Qo : (z == 1) ? Ko : Vo;

    const int tid  = threadIdx.x;
    const int lane = tid & 63;
    const int wave = tid >> 6;
    const int l16  = lane & 15;
    const int quad = lane >> 4;
    const int m_blk = blockIdx.y * 128;
    const int n_blk = blockIdx.x * 128;
    const int m_w = (wave >> 1) * 64;
    const int n_w = (wave & 1) * 64;

    // union: staging 4 x 8192 B / epilogue transpose 4 x 4608 B
    __shared__ __align__(16) char smem[32768];
    bf16_t* As0 = (bf16_t*)smem;
    bf16_t* As1 = (bf16_t*)(smem + 8192);
    bf16_t* Bs0 = (bf16_t*)(smem + 16384);
    bf16_t* Bs1 = (bf16_t*)(smem + 24576);

    floatx4 acc[4][4];
#pragma unroll
    for (int i = 0; i < 4; i++)
#pragma unroll
        for (int j = 0; j < 4; j++) acc[i][j] = (floatx4)0.0f;

    for (int k0 = 0; k0 < HID; k0 += 64) {
        __syncthreads();                                   // WAR on tiles
        stage128x32(X + (size_t)m_blk * HID, HID, k0,      As0, wave, lane);
        stage128x32(X + (size_t)m_blk * HID, HID, k0 + 32, As1, wave, lane);
        stage128x32(W + (size_t)n_blk * HID, HID, k0,      Bs0, wave, lane);
        stage128x32(W + (size_t)n_blk * HID, HID, k0 + 32, Bs1, wave, lane);
        __syncthreads();                                   // staging visible

#pragma unroll
        for (int ks = 0; ks < 2; ks++) {
            bf16_t* As = ks ? As1 : As0;
            bf16_t* Bs = ks ? Bs1 : Bs0;
            bf16x8 a[4], b[4];
#pragma unroll
            for (int i = 0; i < 4; i++) a[i] = *(const bf16x8*)&As[(m_w + i * 16 + l16) * 32 + quad * 8];
#pragma unroll
            for (int j = 0; j < 4; j++) b[j] = *(const bf16x8*)&Bs[(n_w + j * 16 + l16) * 32 + quad * 8];
#pragma unroll
            for (int i = 0; i < 4; i++)
#pragma unroll
                for (int j = 0; j < 4; j++) acc[i][j] = mfma16(a[i], b[j], acc[i][j]);
        }
    }
    __syncthreads();                                       // smem reusable

    float bv_[4];
#pragma unroll
    for (int j = 0; j < 4; j++) bv_[j] = bias[n_blk + n_w + j * 16 + l16];

    if (z != 2) {
        // Q/K [bh][s][d]: per-wave LDS transpose -> coalesced b128 stores.
        const float scale = (z == 0) ? 0.125f : 1.0f;
        bf16_t* Tw = (bf16_t*)(smem + wave * 4608);        // 32 x 72
        const int hN = (n_blk + n_w) >> 6;
#pragma unroll
        for (int ih = 0; ih < 2; ih++) {
#pragma unroll
            for (int i2 = 0; i2 < 2; i2++) {
                const int i = ih * 2 + i2;
#pragma unroll
                for (int j = 0; j < 4; j++)
#pragma unroll
                    for (int r = 0; r < 4; r++)
                        Tw[(i2 * 16 + quad * 4 + r) * 72 + j * 16 + l16] =
                            (bf16_t)((acc[i][j][r] + bv_[j]) * scale);
            }
#pragma unroll
            for (int p = 0; p < 4; p++) {
                const int srow = p * 8 + (lane >> 3);
                const int col  = (lane & 7) * 8;
                bf16x8 v = *(const bf16x8*)&Tw[srow * 72 + col];
                const int m = m_blk + m_w + ih * 32 + srow;
                const int bb = m >> 11, s = m & (SEQ - 1);
                *(bf16x8*)&out[(((size_t)(bb * NHEADS + hN)) * SEQ + s) * HD + col] = v;
            }
        }
    } else {
        // V^T [bh][d][s]: packed b64 stores (s-consecutive per lane).
#pragma unroll
        for (int i = 0; i < 4; i++) {
            const int m = m_blk + m_w + i * 16 + quad * 4;
            const int bb = m >> 11, s = m & (SEQ - 1);
#pragma unroll
            for (int j = 0; j < 4; j++) {
                const int n = n_blk + n_w + j * 16 + l16;
                const int h = n >> 6, d = n & 63;
                bf16x4 pk;
#pragma unroll
                for (int r = 0; r < 4; r++) pk[r] = (bf16_t)(acc[i][j][r] + bv_[j]);
                *(bf16x4*)&out[(((size_t)(bb * NHEADS + h)) * HD + d) * SEQ + s] = pk;
            }
        }
    }
}

// ---------------------------------------------------------------------------
// Kernel 2: flash attention. 4 waves, 16 q/wave, kv tile 64, LDS K/V^T tiles.
// Static-shift softmax with mask folded into a precomputed exp2 addend.
// PV consumes softmax registers directly via K=16 MFMA (no P LDS roundtrip).
// ---------------------------------------------------------------------------
__global__ __launch_bounds__(256, 4) void attn_kernel(
    const bf16_t* __restrict__ Q, const bf16_t* __restrict__ K,
    const bf16_t* __restrict__ Vt, const int* __restrict__ mask,
    bf16_t* __restrict__ ctx)
{
    const int B   = blockIdx.x;            // 0..1023
    const int xcd = B & 7;
    const int idx = B >> 3;                // 0..127
    const int bh  = xcd * 4 + (idx & 3);
    const int q0  = (idx >> 2) * 64;       // block q base
    const int b   = bh >> 4;
    const int h   = bh & 15;
    const int tid  = threadIdx.x;
    const int wave = tid >> 6;
    const int lane = tid & 63;
    const int l16  = lane & 15;
    const int quad = lane >> 4;

    const bf16_t* Qh = Q  + (size_t)bh * SEQ * HD;
    const bf16_t* Kh = K  + (size_t)bh * SEQ * HD;
    const bf16_t* Vh = Vt + (size_t)bh * HD * SEQ;    // [d][s]
    const int*    mk = mask + b * SEQ;

    __shared__ __align__(16) bf16_t Ks[64 * 72];      // K tile [kv][d]; epilogue scratch
    __shared__ __align__(16) bf16_t Vs[64 * 72];      // V^T tile [d][kv]
    __shared__ __align__(16) float  bias2[SEQ];       // (mask? 0 : -1e30) - 26

    // precompute fused mask addend once per block
    for (int i = tid; i < SEQ; i += 256)
        bias2[i] = (mk[i] ? 0.0f : -1.0e30f) - SHIFT2;

    const int qw = q0 + wave * 16;

    bf16x8 bQ[2];
#pragma unroll
    for (int kc = 0; kc < 2; kc++)
        bQ[kc] = ldg8(Qh + (size_t)(qw + l16) * HD + kc * 32 + quad * 8);

    floatx4 O[4];
    floatx4 psum = (floatx4)0.0f;
#pragma unroll
    for (int dt = 0; dt < 4; dt++) O[dt] = (floatx4)0.0f;

    const int r0 = tid >> 3;               // 0..31
    const int c0 = (tid & 7) * 8;          // 0..56

    for (int kt = 0; kt < SEQ; kt += 64) {
        bf16x8 k0v = ldg8(Kh + (size_t)(kt + r0)      * HD + c0);
        bf16x8 k1v = ldg8(Kh + (size_t)(kt + 32 + r0) * HD + c0);
        bf16x8 v0v = ldg8(Vh + (size_t)(r0)      * SEQ + kt + c0);
        bf16x8 v1v = ldg8(Vh + (size_t)(32 + r0) * SEQ + kt + c0);

        __syncthreads();                   // WAR (also covers bias2 on iter 0)
        *(bf16x8*)&Ks[r0 * 72 + c0]        = k0v;
        *(bf16x8*)&Ks[(32 + r0) * 72 + c0] = k1v;
        *(bf16x8*)&Vs[r0 * 72 + c0]        = v0v;
        *(bf16x8*)&Vs[(32 + r0) * 72 + c0] = v1v;
        __syncthreads();                   // RAW

#pragma unroll
        for (int kvt = 0; kvt < 4; kvt++) {
            floatx4 s = (floatx4)0.0f;
#pragma unroll
            for (int kc = 0; kc < 2; kc++) {
                bf16x8 aK = *(const bf16x8*)&Ks[(kvt * 16 + l16) * 72 + kc * 32 + quad * 8];
                s = mfma16(aK, bQ[kc], s);
            }
            const floatx4 ad = *(const floatx4*)&bias2[kt + kvt * 16 + quad * 4];
            floatx4 p;
#pragma unroll
            for (int r = 0; r < 4; r++) p[r] = exp2f(fmaf(s[r], L2E, ad[r]));
            psum += p;
            bf16x4 pb;
#pragma unroll
            for (int r = 0; r < 4; r++) pb[r] = (bf16_t)p[r];
            // PV directly from registers: S^T C-layout == K=16 MFMA B-layout
#pragma unroll
            for (int dt = 0; dt < 4; dt++) {
                bf16x4 aV = *(const bf16x4*)&Vs[(dt * 16 + l16) * 72 + kvt * 16 + quad * 4];
                O[dt] = mfma16k16(aV, pb, O[dt]);
            }
        }
    }

    float su = psum[0] + psum[1] + psum[2] + psum[3];
    su += __shfl_xor(su, 16, 64);
    su += __shfl_xor(su, 32, 64);
    const float linv = (su > 0.0f) ? 1.0f / su : 0.0f;

    __syncthreads();                       // loop reads done; Ks reusable
    bf16_t* Pw = Ks + wave * 1152;         // per-wave 16x72 scratch
#pragma unroll
    for (int dt = 0; dt < 4; dt++) {
        floatx4 o = O[dt] * linv;
        bf16x4 pk;
#pragma unroll
        for (int r = 0; r < 4; r++) pk[r] = (bf16_t)o[r];
        *(bf16x4*)&Pw[l16 * 72 + dt * 16 + quad * 4] = pk;
    }
#pragma unroll
    for (int ch = 0; ch < 2; ch++) {
        const int cc  = ch * 64 + lane;
        const int row = cc >> 3;
        const int col = (cc & 7) * 8;
        bf16x8 vv = *(const bf16x8*)&Pw[row * 72 + col];
        *(bf16x8*)&ctx[((size_t)(b * SEQ + qw + row)) * HID + h * 64 + col] = vv;
    }
}

// ---------------------------------------------------------------------------
// Kernel 3: res = ctx @ Wo^T + bo (residual in ln). BK=64 per barrier-pair.
// ---------------------------------------------------------------------------
__global__ __launch_bounds__(256) void oproj_kernel(
    const bf16_t* __restrict__ C, const bf16_t* __restrict__ Wo,
    const float* __restrict__ bo, float* __restrict__ res)
{
    const int tid  = threadIdx.x;
    const int lane = tid & 63;
    const int wave = tid >> 6;
    const int l16  = lane & 15;
    const int quad = lane >> 4;
    const int m_blk = blockIdx.y * 128;
    const int n_blk = blockIdx.x * 128;
    const int m_w = (wave >> 1) * 64;
    const int n_w = (wave & 1) * 64;

    // union: staging 4 x 8192 B / fp32 transpose 4 x 4352 B
    __shared__ __align__(16) char smem[32768];
    bf16_t* As0 = (bf16_t*)smem;
    bf16_t* As1 = (bf16_t*)(smem + 8192);
    bf16_t* Bs0 = (bf16_t*)(smem + 16384);
    bf16_t* Bs1 = (bf16_t*)(smem + 24576);

    floatx4 acc[4][4];
#pragma unroll
    for (int i = 0; i < 4; i++)
#pragma unroll
        for (int j = 0; j < 4; j++) acc[i][j] = (floatx4)0.0f;

    for (int k0 = 0; k0 < HID; k0 += 64) {
        __syncthreads();
        stage128x32(C  + (size_t)m_blk * HID, HID, k0,      As0, wave, lane);
        stage128x32(C  + (size_t)m_blk * HID, HID, k0 + 32, As1, wave, lane);
        stage128x32(Wo + (size_t)n_blk * HID, HID, k0,      Bs0, wave, lane);
        stage128x32(Wo + (size_t)n_blk * HID, HID, k0 + 32, Bs1, wave, lane);
        __syncthreads();

#pragma unroll
        for (int ks = 0; ks < 2; ks++) {
            bf16_t* As = ks ? As1 : As0;
            bf16_t* Bs = ks ? Bs1 : Bs0;
            bf16x8 a[4], b[4];
#pragma unroll
            for (int i = 0; i < 4; i++) a[i] = *(const bf16x8*)&As[(m_w + i * 16 + l16) * 32 + quad * 8];
#pragma unroll
            for (int j = 0; j < 4; j++) b[j] = *(const bf16x8*)&Bs[(n_w + j * 16 + l16) * 32 + quad * 8];
#pragma unroll
            for (int i = 0; i < 4; i++)
#pragma unroll
                for (int j = 0; j < 4; j++) acc[i][j] = mfma16(a[i], b[j], acc[i][j]);
        }
    }
    __syncthreads();                                       // smem reusable

    float bv_[4];
#pragma unroll
    for (int j = 0; j < 4; j++) bv_[j] = bo[n_blk + n_w + j * 16 + l16];

    float* Tw = (float*)(smem + wave * 4352);              // 16 x 68 fp32
#pragma unroll
    for (int ch = 0; ch < 4; ch++) {
#pragma unroll
        for (int j = 0; j < 4; j++)
#pragma unroll
            for (int r = 0; r < 4; r++)
                Tw[(quad * 4 + r) * 68 + j * 16 + l16] = acc[ch][j][r] + bv_[j];
#pragma unroll
        for (int cc = 0; cc < 4; cc++) {
            const int idx = cc * 64 + lane;                // 0..255
            const int row = idx >> 4;                      // 0..15
            const int col = (idx & 15) * 4;                // 0..60
            float4 v = *(const float4*)&Tw[row * 68 + col];
            const int m = m_blk + m_w + ch * 16 + row;
            *(float4*)&res[(size_t)m * HID + n_blk + n_w + col] = v;
        }
    }
}

// ---------------------------------------------------------------------------
// Kernel 4: LayerNorm((res + X)) over rows of 1024 -> fp32 out
// ---------------------------------------------------------------------------
__global__ __launch_bounds__(256) void ln_kernel(
    const float* __restrict__ res, const float* __restrict__ X,
    const float* __restrict__ g, const float* __restrict__ be,
    float* __restrict__ out)
{
    __shared__ float red1[4], red2[4];
    const int row  = blockIdx.x;
    const int lane = threadIdx.x & 63;
    const int wave = threadIdx.x >> 6;
    const float4 a = ((const float4*)(res + (size_t)row * HID))[threadIdx.x];
    const float4 x = ((const float4*)(X   + (size_t)row * HID))[threadIdx.x];
    float4 v;
    v.x = a.x + x.x; v.y = a.y + x.y; v.z = a.z + x.z; v.w = a.w + x.w;

    float s = v.x + v.y + v.z + v.w;
#pragma unroll
    for (int off = 1; off < 64; off <<= 1) s += __shfl_xor(s, off, 64);
    if (lane == 0) red1[wave] = s;
    __syncthreads();
    const float mu = (red1[0] + red1[1] + red1[2] + red1[3]) * (1.0f / HID);

    const float d0 = v.x - mu, d1 = v.y - mu, d2 = v.z - mu, d3 = v.w - mu;
    float ss = d0 * d0 + d1 * d1 + d2 * d2 + d3 * d3;
#pragma unroll
    for (int off = 1; off < 64; off <<= 1) ss += __shfl_xor(ss, off, 64);
    if (lane == 0) red2[wave] = ss;
    __syncthreads();
    const float var = (red2[0] + red2[1] + red2[2] + red2[3]) * (1.0f / HID);
    const float rstd = rsqrtf(var + LNEPS);

    const float4 gv = ((const float4*)g)[threadIdx.x];
    const float4 bv = ((const float4*)be)[threadIdx.x];
    float4 o;
    o.x = d0 * rstd * gv.x + bv.x;
    o.y = d1 * rstd * gv.y + bv.y;
    o.z = d2 * rstd * gv.z + bv.z;
    o.w = d3 * rstd * gv.w + bv.w;
    ((float4*)(out + (size_t)row * HID))[threadIdx.x] = o;
}

// ---------------------------------------------------------------------------
extern "C" void kernel_launch(void* const* d_in, const int* in_sizes, int n_in,
                              void* d_out, int out_size, void* d_ws, size_t ws_size,
                              hipStream_t stream)
{
    const float* X  = (const float*)d_in[0];
    const int* mask = (const int*)d_in[1];
    const float* Wq = (const float*)d_in[2];  const float* bq = (const float*)d_in[3];
    const float* Wk = (const float*)d_in[4];  const float* bk = (const float*)d_in[5];
    const float* Wv = (const float*)d_in[6];  const float* bv = (const float*)d_in[7];
    const float* Wo = (const float*)d_in[8];  const float* bo = (const float*)d_in[9];
    const float* g  = (const float*)d_in[10]; const float* be = (const float*)d_in[11];
    float* out = (float*)d_out;

    char* ws = (char*)d_ws;
    bf16_t* Qb  = (bf16_t*)(ws);                          // [0, 8M)
    bf16_t* Kb  = (bf16_t*)(ws + (8ull  << 20));          // [8M, 16M)
    bf16_t* Vb  = (bf16_t*)(ws + (16ull << 20));          // [16M, 24M)  V^T [bh][d][s]
    bf16_t* Cb  = (bf16_t*)(ws + (24ull << 20));          // [24M, 32M)
    float*  Rb  = (float*)(ws);                           // [0, 16M) aliases dead Q/K
    bf16_t* Xc  = (bf16_t*)(ws + (32ull << 20));          // [32M, 40M)
    bf16_t* Wqc = (bf16_t*)(ws + (40ull << 20));
    bf16_t* Wkc = (bf16_t*)(ws + (42ull << 20));
    bf16_t* Wvc = (bf16_t*)(ws + (44ull << 20));
    bf16_t* Woc = (bf16_t*)(ws + (46ull << 20));

    cvt_kernel <<<dim3(128, 1, 5), 256, 0, stream>>>(X, Wq, Wk, Wv, Wo, Xc, Wqc, Wkc, Wvc, Woc);
    qkv_kernel <<<dim3(8, 32, 3), 256, 0, stream>>>(Xc, Wqc, bq, Wkc, bk, Wvc, bv, Qb, Kb, Vb);
    attn_kernel<<<dim3(32 * 32), 256, 0, stream>>>(Qb, Kb, Vb, mask, Cb);
    oproj_kernel<<<dim3(8, 32), 256, 0, stream>>>(Cb, Woc, bo, Rb);
    ln_kernel  <<<MTOT, 256, 0, stream>>>(Rb, X, g, be, out);
}

// Round 11
// 236.518 us; speedup vs baseline: 1.0953x; 1.0953x over previous
//
#include <hip/hip_runtime.h>
#include <hip/hip_bf16.h>

// Problem: B=2, S=2048, H=1024, HEADS=16, HEAD_DIM=64. Wire dtype fp32; output fp32.
// R11: GEMMs reverted to R9 BK=32 (BK=64 LDS-occupancy regression, m132 redux).
// attn keeps R10 register-PV (K=16 MFMA) but exp2f -> __builtin_amdgcn_exp2f
// (single v_exp_f32 instead of ~10-instr OCML expansion; ~40% of attn VALU).
#define SEQ     2048
#define BATCH   2
#define HID     1024
#define NHEADS  16
#define HD      64
#define MTOT    4096            // BATCH*SEQ
#define LNEPS   1e-6f
#define L2E     1.4426950408889634f
#define SHIFT2  26.0f           // base-2 static softmax shift

typedef __bf16 bf16_t;
typedef bf16_t bf16x8 __attribute__((ext_vector_type(8)));   // 4 VGPRs = K=32 MFMA A/B frag
typedef bf16_t bf16x4 __attribute__((ext_vector_type(4)));   // 2 VGPRs = K=16 MFMA A/B frag
typedef short  short4v __attribute__((ext_vector_type(4)));
typedef float  floatx4 __attribute__((ext_vector_type(4)));  // MFMA C/D frag

__device__ __forceinline__ floatx4 mfma16(bf16x8 a, bf16x8 b, floatx4 c) {
    return __builtin_amdgcn_mfma_f32_16x16x32_bf16(a, b, c, 0, 0, 0);
}
// K=16 bf16 MFMA (v_mfma_f32_16x16x16_bf16, 2-reg operands)
__device__ __forceinline__ floatx4 mfma16k16(bf16x4 a, bf16x4 b, floatx4 c) {
    short4v as = __builtin_bit_cast(short4v, a);
    short4v bs = __builtin_bit_cast(short4v, b);
    return __builtin_amdgcn_mfma_f32_16x16x16bf16_1k(as, bs, c, 0, 0, 0);
}
__device__ __forceinline__ bf16x8 ldg8(const bf16_t* p) { return *(const bf16x8*)p; }

// Stage one 128x32 bf16 tile into LDS via global_load_lds width 16.
__device__ __forceinline__ void stage128x32(const bf16_t* __restrict__ g, int row_stride,
                                            int k0, bf16_t* lds, int wave, int lane)
{
#pragma unroll
    for (int j = 0; j < 2; j++) {
        const int rbase = wave * 32 + j * 16;
        const bf16_t* src = g + (size_t)(rbase + (lane >> 2)) * row_stride + k0 + (lane & 3) * 8;
        bf16_t* dst = lds + rbase * 32;
        __builtin_amdgcn_global_load_lds(
            (const __attribute__((address_space(1))) unsigned int*)src,
            (__attribute__((address_space(3))) unsigned int*)dst, 16, 0, 0);
    }
}

// ---------------------------------------------------------------------------
// Kernel 0: fp32 -> bf16 conversion for X, Wq, Wk, Wv, Wo.
// ---------------------------------------------------------------------------
__global__ __launch_bounds__(256) void cvt_kernel(
    const float* sX, const float* sWq, const float* sWk, const float* sWv, const float* sWo,
    bf16_t* dX, bf16_t* dWq, bf16_t* dWk, bf16_t* dWv, bf16_t* dWo)
{
    const int z = blockIdx.z;
    const float* src; bf16_t* dst; int n;
    switch (z) {
        case 0:  src = sX;  dst = dX;  n = MTOT * HID; break;
        case 1:  src = sWq; dst = dWq; n = HID * HID;  break;
        case 2:  src = sWk; dst = dWk; n = HID * HID;  break;
        case 3:  src = sWv; dst = dWv; n = HID * HID;  break;
        default: src = sWo; dst = dWo; n = HID * HID;  break;
    }
    const int n4 = n >> 2;
    const int stride = gridDim.x * blockDim.x;
    for (int i = blockIdx.x * blockDim.x + threadIdx.x; i < n4; i += stride) {
        const float4 v = ((const float4*)src)[i];
        bf16_t o[4] = {(bf16_t)v.x, (bf16_t)v.y, (bf16_t)v.z, (bf16_t)v.w};
        *(unsigned long long*)(dst + 4 * i) = *(unsigned long long*)o;
    }
}

// ---------------------------------------------------------------------------
// Kernel 1: QKV projection (NT GEMM, m97 staging, BK=32 — R9 config).
// Q pre-scaled by 0.125. Q,K stored [bh][s][d]; V TRANSPOSED [bh][d][s].
// ---------------------------------------------------------------------------
__global__ __launch_bounds__(256) void qkv_kernel(
    const bf16_t* __restrict__ X,
    const bf16_t* __restrict__ Wq, const float* __restrict__ bq,
    const bf16_t* __restrict__ Wk, const float* __restrict__ bk,
    const bf16_t* __restrict__ Wv, const float* __restrict__ bv,
    bf16_t* __restrict__ Qo, bf16_t* __restrict__ Ko, bf16_t* __restrict__ Vo)
{
    const int z = blockIdx.z;
    const bf16_t* W    = (z == 0) ? Wq : (z == 1) ? Wk : Wv;
    const float*  bias = (z == 0) ? bq : (z == 1) ? bk : bv;
    bf16_t*       out  = (z == 0) ? Qo : (z == 1) ? Ko : Vo;

    const int tid  = threadIdx.x;
    const int lane = tid & 63;
    const int wave = tid >> 6;
    const int l16  = lane & 15;
    const int quad = lane >> 4;
    const int m_blk = blockIdx.y * 128;
    const int n_blk = blockIdx.x * 128;
    const int m_w = (wave >> 1) * 64;
    const int n_w = (wave & 1) * 64;

    // union: staging (2 x 8192 B) / epilogue transpose (4 x 4608 B)
    __shared__ __align__(16) char smem[18432];
    bf16_t* As = (bf16_t*)smem;
    bf16_t* Bs = (bf16_t*)(smem + 8192);

    floatx4 acc[4][4];
#pragma unroll
    for (int i = 0; i < 4; i++)
#pragma unroll
        for (int j = 0; j < 4; j++) acc[i][j] = (floatx4)0.0f;

    for (int k0 = 0; k0 < HID; k0 += 32) {
        __syncthreads();                                   // WAR on tiles
        stage128x32(X + (size_t)m_blk * HID, HID, k0, As, wave, lane);
        stage128x32(W + (size_t)n_blk * HID, HID, k0, Bs, wave, lane);
        __syncthreads();                                   // staging visible

        bf16x8 a[4], b[4];
#pragma unroll
        for (int i = 0; i < 4; i++) a[i] = *(const bf16x8*)&As[(m_w + i * 16 + l16) * 32 + quad * 8];
#pragma unroll
        for (int j = 0; j < 4; j++) b[j] = *(const bf16x8*)&Bs[(n_w + j * 16 + l16) * 32 + quad * 8];
#pragma unroll
        for (int i = 0; i < 4; i++)
#pragma unroll
            for (int j = 0; j < 4; j++) acc[i][j] = mfma16(a[i], b[j], acc[i][j]);
    }
    __syncthreads();                                       // smem reusable

    float bv_[4];
#pragma unroll
    for (int j = 0; j < 4; j++) bv_[j] = bias[n_blk + n_w + j * 16 + l16];

    if (z != 2) {
        // Q/K [bh][s][d]: per-wave LDS transpose -> coalesced b128 stores.
        const float scale = (z == 0) ? 0.125f : 1.0f;
        bf16_t* Tw = (bf16_t*)(smem + wave * 4608);        // 32 x 72
        const int hN = (n_blk + n_w) >> 6;
#pragma unroll
        for (int ih = 0; ih < 2; ih++) {
#pragma unroll
            for (int i2 = 0; i2 < 2; i2++) {
                const int i = ih * 2 + i2;
#pragma unroll
                for (int j = 0; j < 4; j++)
#pragma unroll
                    for (int r = 0; r < 4; r++)
                        Tw[(i2 * 16 + quad * 4 + r) * 72 + j * 16 + l16] =
                            (bf16_t)((acc[i][j][r] + bv_[j]) * scale);
            }
#pragma unroll
            for (int p = 0; p < 4; p++) {
                const int srow = p * 8 + (lane >> 3);
                const int col  = (lane & 7) * 8;
                bf16x8 v = *(const bf16x8*)&Tw[srow * 72 + col];
                const int m = m_blk + m_w + ih * 32 + srow;
                const int bb = m >> 11, s = m & (SEQ - 1);
                *(bf16x8*)&out[(((size_t)(bb * NHEADS + hN)) * SEQ + s) * HD + col] = v;
            }
        }
    } else {
        // V^T [bh][d][s]: packed b64 stores (s-consecutive per lane).
#pragma unroll
        for (int i = 0; i < 4; i++) {
            const int m = m_blk + m_w + i * 16 + quad * 4;
            const int bb = m >> 11, s = m & (SEQ - 1);
#pragma unroll
            for (int j = 0; j < 4; j++) {
                const int n = n_blk + n_w + j * 16 + l16;
                const int h = n >> 6, d = n & 63;
                bf16x4 pk;
#pragma unroll
                for (int r = 0; r < 4; r++) pk[r] = (bf16_t)(acc[i][j][r] + bv_[j]);
                *(bf16x4*)&out[(((size_t)(bb * NHEADS + h)) * HD + d) * SEQ + s] = pk;
            }
        }
    }
}

// ---------------------------------------------------------------------------
// Kernel 2: flash attention. 4 waves, 16 q/wave, kv tile 64, LDS K/V^T tiles.
// Static-shift softmax with precomputed mask addend; raw v_exp_f32.
// PV via K=16 MFMA directly from softmax registers (no P LDS roundtrip).
// ---------------------------------------------------------------------------
__global__ __launch_bounds__(256, 4) void attn_kernel(
    const bf16_t* __restrict__ Q, const bf16_t* __restrict__ K,
    const bf16_t* __restrict__ Vt, const int* __restrict__ mask,
    bf16_t* __restrict__ ctx)
{
    const int B   = blockIdx.x;            // 0..1023
    const int xcd = B & 7;
    const int idx = B >> 3;                // 0..127
    const int bh  = xcd * 4 + (idx & 3);
    const int q0  = (idx >> 2) * 64;       // block q base
    const int b   = bh >> 4;
    const int h   = bh & 15;
    const int tid  = threadIdx.x;
    const int wave = tid >> 6;
    const int lane = tid & 63;
    const int l16  = lane & 15;
    const int quad = lane >> 4;

    const bf16_t* Qh = Q  + (size_t)bh * SEQ * HD;
    const bf16_t* Kh = K  + (size_t)bh * SEQ * HD;
    const bf16_t* Vh = Vt + (size_t)bh * HD * SEQ;    // [d][s]
    const int*    mk = mask + b * SEQ;

    __shared__ __align__(16) bf16_t Ks[64 * 72];      // K tile [kv][d]; epilogue scratch
    __shared__ __align__(16) bf16_t Vs[64 * 72];      // V^T tile [d][kv]
    __shared__ __align__(16) float  bias2[SEQ];       // (mask? 0 : -1e30) - 26

    for (int i = tid; i < SEQ; i += 256)
        bias2[i] = (mk[i] ? 0.0f : -1.0e30f) - SHIFT2;

    const int qw = q0 + wave * 16;

    bf16x8 bQ[2];
#pragma unroll
    for (int kc = 0; kc < 2; kc++)
        bQ[kc] = ldg8(Qh + (size_t)(qw + l16) * HD + kc * 32 + quad * 8);

    floatx4 O[4];
    floatx4 psum = (floatx4)0.0f;
#pragma unroll
    for (int dt = 0; dt < 4; dt++) O[dt] = (floatx4)0.0f;

    const int r0 = tid >> 3;               // 0..31
    const int c0 = (tid & 7) * 8;          // 0..56

    for (int kt = 0; kt < SEQ; kt += 64) {
        bf16x8 k0v = ldg8(Kh + (size_t)(kt + r0)      * HD + c0);
        bf16x8 k1v = ldg8(Kh + (size_t)(kt + 32 + r0) * HD + c0);
        bf16x8 v0v = ldg8(Vh + (size_t)(r0)      * SEQ + kt + c0);
        bf16x8 v1v = ldg8(Vh + (size_t)(32 + r0) * SEQ + kt + c0);

        __syncthreads();                   // WAR (covers bias2 on iter 0)
        *(bf16x8*)&Ks[r0 * 72 + c0]        = k0v;
        *(bf16x8*)&Ks[(32 + r0) * 72 + c0] = k1v;
        *(bf16x8*)&Vs[r0 * 72 + c0]        = v0v;
        *(bf16x8*)&Vs[(32 + r0) * 72 + c0] = v1v;
        __syncthreads();                   // RAW

#pragma unroll
        for (int kvt = 0; kvt < 4; kvt++) {
            floatx4 s = (floatx4)0.0f;
#pragma unroll
            for (int kc = 0; kc < 2; kc++) {
                bf16x8 aK = *(const bf16x8*)&Ks[(kvt * 16 + l16) * 72 + kc * 32 + quad * 8];
                s = mfma16(aK, bQ[kc], s);
            }
            const floatx4 ad = *(const floatx4*)&bias2[kt + kvt * 16 + quad * 4];
            floatx4 p;
#pragma unroll
            for (int r = 0; r < 4; r++)
                p[r] = __builtin_amdgcn_exp2f(fmaf(s[r], L2E, ad[r]));  // raw v_exp_f32
            psum += p;
            bf16x4 pb;
#pragma unroll
            for (int r = 0; r < 4; r++) pb[r] = (bf16_t)p[r];
            // PV directly from registers: S^T C-layout == K=16 MFMA B-layout
#pragma unroll
            for (int dt = 0; dt < 4; dt++) {
                bf16x4 aV = *(const bf16x4*)&Vs[(dt * 16 + l16) * 72 + kvt * 16 + quad * 4];
                O[dt] = mfma16k16(aV, pb, O[dt]);
            }
        }
    }

    float su = psum[0] + psum[1] + psum[2] + psum[3];
    su += __shfl_xor(su, 16, 64);
    su += __shfl_xor(su, 32, 64);
    const float linv = (su > 0.0f) ? 1.0f / su : 0.0f;

    __syncthreads();                       // loop reads done; Ks reusable
    bf16_t* Pw = Ks + wave * 1152;         // per-wave 16x72 scratch
#pragma unroll
    for (int dt = 0; dt < 4; dt++) {
        floatx4 o = O[dt] * linv;
        bf16x4 pk;
#pragma unroll
        for (int r = 0; r < 4; r++) pk[r] = (bf16_t)o[r];
        *(bf16x4*)&Pw[l16 * 72 + dt * 16 + quad * 4] = pk;
    }
#pragma unroll
    for (int ch = 0; ch < 2; ch++) {
        const int cc  = ch * 64 + lane;
        const int row = cc >> 3;
        const int col = (cc & 7) * 8;
        bf16x8 vv = *(const bf16x8*)&Pw[row * 72 + col];
        *(bf16x8*)&ctx[((size_t)(b * SEQ + qw + row)) * HID + h * 64 + col] = vv;
    }
}

// ---------------------------------------------------------------------------
// Kernel 3: res = ctx @ Wo^T + bo (residual in ln). BK=32 — R9 config.
// ---------------------------------------------------------------------------
__global__ __launch_bounds__(256) void oproj_kernel(
    const bf16_t* __restrict__ C, const bf16_t* __restrict__ Wo,
    const float* __restrict__ bo, float* __restrict__ res)
{
    const int tid  = threadIdx.x;
    const int lane = tid & 63;
    const int wave = tid >> 6;
    const int l16  = lane & 15;
    const int quad = lane >> 4;
    const int m_blk = blockIdx.y * 128;
    const int n_blk = blockIdx.x * 128;
    const int m_w = (wave >> 1) * 64;
    const int n_w = (wave & 1) * 64;

    // union: staging (16384 B) / fp32 transpose (4 x 4352 B)
    __shared__ __align__(16) char smem[17408];
    bf16_t* As = (bf16_t*)smem;
    bf16_t* Bs = (bf16_t*)(smem + 8192);

    floatx4 acc[4][4];
#pragma unroll
    for (int i = 0; i < 4; i++)
#pragma unroll
        for (int j = 0; j < 4; j++) acc[i][j] = (floatx4)0.0f;

    for (int k0 = 0; k0 < HID; k0 += 32) {
        __syncthreads();
        stage128x32(C  + (size_t)m_blk * HID, HID, k0, As, wave, lane);
        stage128x32(Wo + (size_t)n_blk * HID, HID, k0, Bs, wave, lane);
        __syncthreads();

        bf16x8 a[4], b[4];
#pragma unroll
        for (int i = 0; i < 4; i++) a[i] = *(const bf16x8*)&As[(m_w + i * 16 + l16) * 32 + quad * 8];
#pragma unroll
        for (int j = 0; j < 4; j++) b[j] = *(const bf16x8*)&Bs[(n_w + j * 16 + l16) * 32 + quad * 8];
#pragma unroll
        for (int i = 0; i < 4; i++)
#pragma unroll
            for (int j = 0; j < 4; j++) acc[i][j] = mfma16(a[i], b[j], acc[i][j]);
    }
    __syncthreads();                                       // smem reusable

    float bv_[4];
#pragma unroll
    for (int j = 0; j < 4; j++) bv_[j] = bo[n_blk + n_w + j * 16 + l16];

    float* Tw = (float*)(smem + wave * 4352);              // 16 x 68 fp32
#pragma unroll
    for (int ch = 0; ch < 4; ch++) {
#pragma unroll
        for (int j = 0; j < 4; j++)
#pragma unroll
            for (int r = 0; r < 4; r++)
                Tw[(quad * 4 + r) * 68 + j * 16 + l16] = acc[ch][j][r] + bv_[j];
#pragma unroll
        for (int cc = 0; cc < 4; cc++) {
            const int idx = cc * 64 + lane;                // 0..255
            const int row = idx >> 4;                      // 0..15
            const int col = (idx & 15) * 4;                // 0..60
            float4 v = *(const float4*)&Tw[row * 68 + col];
            const int m = m_blk + m_w + ch * 16 + row;
            *(float4*)&res[(size_t)m * HID + n_blk + n_w + col] = v;
        }
    }
}

// ---------------------------------------------------------------------------
// Kernel 4: LayerNorm((res + X)) over rows of 1024 -> fp32 out
// ---------------------------------------------------------------------------
__global__ __launch_bounds__(256) void ln_kernel(
    const float* __restrict__ res, const float* __restrict__ X,
    const float* __restrict__ g, const float* __restrict__ be,
    float* __restrict__ out)
{
    __shared__ float red1[4], red2[4];
    const int row  = blockIdx.x;
    const int lane = threadIdx.x & 63;
    const int wave = threadIdx.x >> 6;
    const float4 a = ((const float4*)(res + (size_t)row * HID))[threadIdx.x];
    const float4 x = ((const float4*)(X   + (size_t)row * HID))[threadIdx.x];
    float4 v;
    v.x = a.x + x.x; v.y = a.y + x.y; v.z = a.z + x.z; v.w = a.w + x.w;

    float s = v.x + v.y + v.z + v.w;
#pragma unroll
    for (int off = 1; off < 64; off <<= 1) s += __shfl_xor(s, off, 64);
    if (lane == 0) red1[wave] = s;
    __syncthreads();
    const float mu = (red1[0] + red1[1] + red1[2] + red1[3]) * (1.0f / HID);

    const float d0 = v.x - mu, d1 = v.y - mu, d2 = v.z - mu, d3 = v.w - mu;
    float ss = d0 * d0 + d1 * d1 + d2 * d2 + d3 * d3;
#pragma unroll
    for (int off = 1; off < 64; off <<= 1) ss += __shfl_xor(ss, off, 64);
    if (lane == 0) red2[wave] = ss;
    __syncthreads();
    const float var = (red2[0] + red2[1] + red2[2] + red2[3]) * (1.0f / HID);
    const float rstd = rsqrtf(var + LNEPS);

    const float4 gv = ((const float4*)g)[threadIdx.x];
    const float4 bv = ((const float4*)be)[threadIdx.x];
    float4 o;
    o.x = d0 * rstd * gv.x + bv.x;
    o.y = d1 * rstd * gv.y + bv.y;
    o.z = d2 * rstd * gv.z + bv.z;
    o.w = d3 * rstd * gv.w + bv.w;
    ((float4*)(out + (size_t)row * HID))[threadIdx.x] = o;
}

// ---------------------------------------------------------------------------
extern "C" void kernel_launch(void* const* d_in, const int* in_sizes, int n_in,
                              void* d_out, int out_size, void* d_ws, size_t ws_size,
                              hipStream_t stream)
{
    const float* X  = (const float*)d_in[0];
    const int* mask = (const int*)d_in[1];
    const float* Wq = (const float*)d_in[2];  const float* bq = (const float*)d_in[3];
    const float* Wk = (const float*)d_in[4];  const float* bk = (const float*)d_in[5];
    const float* Wv = (const float*)d_in[6];  const float* bv = (const float*)d_in[7];
    const float* Wo = (const float*)d_in[8];  const float* bo = (const float*)d_in[9];
    const float* g  = (const float*)d_in[10]; const float* be = (const float*)d_in[11];
    float* out = (float*)d_out;

    char* ws = (char*)d_ws;
    bf16_t* Qb  = (bf16_t*)(ws);                          // [0, 8M)
    bf16_t* Kb  = (bf16_t*)(ws + (8ull  << 20));          // [8M, 16M)
    bf16_t* Vb  = (bf16_t*)(ws + (16ull << 20));          // [16M, 24M)  V^T [bh][d][s]
    bf16_t* Cb  = (bf16_t*)(ws + (24ull << 20));          // [24M, 32M)
    float*  Rb  = (float*)(ws);                           // [0, 16M) aliases dead Q/K
    bf16_t* Xc  = (bf16_t*)(ws + (32ull << 20));          // [32M, 40M)
    bf16_t* Wqc = (bf16_t*)(ws + (40ull << 20));
    bf16_t* Wkc = (bf16_t*)(ws + (42ull << 20));
    bf16_t* Wvc = (bf16_t*)(ws + (44ull << 20));
    bf16_t* Woc = (bf16_t*)(ws + (46ull << 20));

    cvt_kernel <<<dim3(128, 1, 5), 256, 0, stream>>>(X, Wq, Wk, Wv, Wo, Xc, Wqc, Wkc, Wvc, Woc);
    qkv_kernel <<<dim3(8, 32, 3), 256, 0, stream>>>(Xc, Wqc, bq, Wkc, bk, Wvc, bv, Qb, Kb, Vb);
    attn_kernel<<<dim3(32 * 32), 256, 0, stream>>>(Qb, Kb, Vb, mask, Cb);
    oproj_kernel<<<dim3(8, 32), 256, 0, stream>>>(Cb, Woc, bo, Rb);
    ln_kernel  <<<MTOT, 256, 0, stream>>>(Rb, X, g, be, out);
}

// Round 12
// 227.903 us; speedup vs baseline: 1.1367x; 1.0378x over previous
//
#include <hip/hip_runtime.h>
#include <hip/hip_bf16.h>

// Problem: B=2, S=2048, H=1024, HEADS=16, HEAD_DIM=64. Wire dtype fp32; output fp32.
// R12: (a) attn: software-pipelined global->reg prefetch of next kv tile before
// compute (hides L2 latency behind compute). (b) oproj: 64x128 tiles -> 512
// blocks = 2/CU (was 1/CU, fully exposed barriers). (c) qkv V^T epilogue via
// per-wave LDS transpose -> coalesced b128 stores (was d-strided b64 scatter).
#define SEQ     2048
#define BATCH   2
#define HID     1024
#define NHEADS  16
#define HD      64
#define MTOT    4096            // BATCH*SEQ
#define LNEPS   1e-6f
#define L2E     1.4426950408889634f
#define SHIFT2  26.0f           // base-2 static softmax shift

typedef __bf16 bf16_t;
typedef bf16_t bf16x8 __attribute__((ext_vector_type(8)));   // 4 VGPRs = K=32 MFMA A/B frag
typedef bf16_t bf16x4 __attribute__((ext_vector_type(4)));   // 2 VGPRs = K=16 MFMA A/B frag
typedef short  short4v __attribute__((ext_vector_type(4)));
typedef float  floatx4 __attribute__((ext_vector_type(4)));  // MFMA C/D frag

__device__ __forceinline__ floatx4 mfma16(bf16x8 a, bf16x8 b, floatx4 c) {
    return __builtin_amdgcn_mfma_f32_16x16x32_bf16(a, b, c, 0, 0, 0);
}
// K=16 bf16 MFMA (v_mfma_f32_16x16x16_bf16, 2-reg operands)
__device__ __forceinline__ floatx4 mfma16k16(bf16x4 a, bf16x4 b, floatx4 c) {
    short4v as = __builtin_bit_cast(short4v, a);
    short4v bs = __builtin_bit_cast(short4v, b);
    return __builtin_amdgcn_mfma_f32_16x16x16bf16_1k(as, bs, c, 0, 0, 0);
}
__device__ __forceinline__ bf16x8 ldg8(const bf16_t* p) { return *(const bf16x8*)p; }

// Stage one 128x32 bf16 tile into LDS via global_load_lds width 16.
__device__ __forceinline__ void stage128x32(const bf16_t* __restrict__ g, int row_stride,
                                            int k0, bf16_t* lds, int wave, int lane)
{
#pragma unroll
    for (int j = 0; j < 2; j++) {
        const int rbase = wave * 32 + j * 16;
        const bf16_t* src = g + (size_t)(rbase + (lane >> 2)) * row_stride + k0 + (lane & 3) * 8;
        bf16_t* dst = lds + rbase * 32;
        __builtin_amdgcn_global_load_lds(
            (const __attribute__((address_space(1))) unsigned int*)src,
            (__attribute__((address_space(3))) unsigned int*)dst, 16, 0, 0);
    }
}
// Stage one 64x32 bf16 tile (wave w covers rows [w*16, w*16+16)).
__device__ __forceinline__ void stage64x32(const bf16_t* __restrict__ g, int row_stride,
                                           int k0, bf16_t* lds, int wave, int lane)
{
    const int rbase = wave * 16;
    const bf16_t* src = g + (size_t)(rbase + (lane >> 2)) * row_stride + k0 + (lane & 3) * 8;
    bf16_t* dst = lds + rbase * 32;
    __builtin_amdgcn_global_load_lds(
        (const __attribute__((address_space(1))) unsigned int*)src,
        (__attribute__((address_space(3))) unsigned int*)dst, 16, 0, 0);
}

// ---------------------------------------------------------------------------
// Kernel 0: fp32 -> bf16 conversion for X, Wq, Wk, Wv, Wo.
// ---------------------------------------------------------------------------
__global__ __launch_bounds__(256) void cvt_kernel(
    const float* sX, const float* sWq, const float* sWk, const float* sWv, const float* sWo,
    bf16_t* dX, bf16_t* dWq, bf16_t* dWk, bf16_t* dWv, bf16_t* dWo)
{
    const int z = blockIdx.z;
    const float* src; bf16_t* dst; int n;
    switch (z) {
        case 0:  src = sX;  dst = dX;  n = MTOT * HID; break;
        case 1:  src = sWq; dst = dWq; n = HID * HID;  break;
        case 2:  src = sWk; dst = dWk; n = HID * HID;  break;
        case 3:  src = sWv; dst = dWv; n = HID * HID;  break;
        default: src = sWo; dst = dWo; n = HID * HID;  break;
    }
    const int n4 = n >> 2;
    const int stride = gridDim.x * blockDim.x;
    for (int i = blockIdx.x * blockDim.x + threadIdx.x; i < n4; i += stride) {
        const float4 v = ((const float4*)src)[i];
        bf16_t o[4] = {(bf16_t)v.x, (bf16_t)v.y, (bf16_t)v.z, (bf16_t)v.w};
        *(unsigned long long*)(dst + 4 * i) = *(unsigned long long*)o;
    }
}

// ---------------------------------------------------------------------------
// Kernel 1: QKV projection (NT GEMM, m97 staging, BK=32).
// Q pre-scaled by 0.125. Q,K stored [bh][s][d]; V TRANSPOSED [bh][d][s].
// Both epilogues now LDS-transposed coalesced stores.
// ---------------------------------------------------------------------------
__global__ __launch_bounds__(256) void qkv_kernel(
    const bf16_t* __restrict__ X,
    const bf16_t* __restrict__ Wq, const float* __restrict__ bq,
    const bf16_t* __restrict__ Wk, const float* __restrict__ bk,
    const bf16_t* __restrict__ Wv, const float* __restrict__ bv,
    bf16_t* __restrict__ Qo, bf16_t* __restrict__ Ko, bf16_t* __restrict__ Vo)
{
    const int z = blockIdx.z;
    const bf16_t* W    = (z == 0) ? Wq : (z == 1) ? Wk : Wv;
    const float*  bias = (z == 0) ? bq : (z == 1) ? bk : bv;
    bf16_t*       out  = (z == 0) ? Qo : (z == 1) ? Ko : Vo;

    const int tid  = threadIdx.x;
    const int lane = tid & 63;
    const int wave = tid >> 6;
    const int l16  = lane & 15;
    const int quad = lane >> 4;
    const int m_blk = blockIdx.y * 128;
    const int n_blk = blockIdx.x * 128;
    const int m_w = (wave >> 1) * 64;
    const int n_w = (wave & 1) * 64;

    // union: staging (2 x 8192 B) / epilogue transpose (4 x 4608 B)
    __shared__ __align__(16) char smem[18432];
    bf16_t* As = (bf16_t*)smem;
    bf16_t* Bs = (bf16_t*)(smem + 8192);

    floatx4 acc[4][4];
#pragma unroll
    for (int i = 0; i < 4; i++)
#pragma unroll
        for (int j = 0; j < 4; j++) acc[i][j] = (floatx4)0.0f;

    for (int k0 = 0; k0 < HID; k0 += 32) {
        __syncthreads();                                   // WAR on tiles
        stage128x32(X + (size_t)m_blk * HID, HID, k0, As, wave, lane);
        stage128x32(W + (size_t)n_blk * HID, HID, k0, Bs, wave, lane);
        __syncthreads();                                   // staging visible

        bf16x8 a[4], b[4];
#pragma unroll
        for (int i = 0; i < 4; i++) a[i] = *(const bf16x8*)&As[(m_w + i * 16 + l16) * 32 + quad * 8];
#pragma unroll
        for (int j = 0; j < 4; j++) b[j] = *(const bf16x8*)&Bs[(n_w + j * 16 + l16) * 32 + quad * 8];
#pragma unroll
        for (int i = 0; i < 4; i++)
#pragma unroll
            for (int j = 0; j < 4; j++) acc[i][j] = mfma16(a[i], b[j], acc[i][j]);
    }
    __syncthreads();                                       // smem reusable

    float bv_[4];
#pragma unroll
    for (int j = 0; j < 4; j++) bv_[j] = bias[n_blk + n_w + j * 16 + l16];

    bf16_t* Tw = (bf16_t*)(smem + wave * 4608);            // per-wave 32 x 72

    if (z != 2) {
        // Q/K [bh][s][d]: LDS transpose (rows=s) -> coalesced b128 stores.
        const float scale = (z == 0) ? 0.125f : 1.0f;
        const int hN = (n_blk + n_w) >> 6;
#pragma unroll
        for (int ih = 0; ih < 2; ih++) {
#pragma unroll
            for (int i2 = 0; i2 < 2; i2++) {
                const int i = ih * 2 + i2;
#pragma unroll
                for (int j = 0; j < 4; j++)
#pragma unroll
                    for (int r = 0; r < 4; r++)
                        Tw[(i2 * 16 + quad * 4 + r) * 72 + j * 16 + l16] =
                            (bf16_t)((acc[i][j][r] + bv_[j]) * scale);
            }
#pragma unroll
            for (int p = 0; p < 4; p++) {
                const int srow = p * 8 + (lane >> 3);
                const int col  = (lane & 7) * 8;
                bf16x8 v = *(const bf16x8*)&Tw[srow * 72 + col];
                const int m = m_blk + m_w + ih * 32 + srow;
                const int bb = m >> 11, s = m & (SEQ - 1);
                *(bf16x8*)&out[(((size_t)(bb * NHEADS + hN)) * SEQ + s) * HD + col] = v;
            }
        }
    } else {
        // V^T [bh][d][s]: LDS transpose (rows=d, cols=s) -> coalesced b128
        // stores along s. Two chunks of 32 d each.
        const int m0 = m_blk + m_w;                        // 64-aligned
        const int bb = m0 >> 11, s0 = m0 & (SEQ - 1);
#pragma unroll
        for (int jh = 0; jh < 2; jh++) {
#pragma unroll
            for (int j2 = 0; j2 < 2; j2++) {
                const int j = jh * 2 + j2;
#pragma unroll
                for (int i = 0; i < 4; i++) {
                    bf16x4 pk;
#pragma unroll
                    for (int r = 0; r < 4; r++) pk[r] = (bf16_t)(acc[i][j][r] + bv_[j]);
                    *(bf16x4*)&Tw[(j2 * 16 + l16) * 72 + i * 16 + quad * 4] = pk;
                }
            }
#pragma unroll
            for (int p = 0; p < 4; p++) {
                const int srow = p * 8 + (lane >> 3);      // d-local 0..31
                const int col  = (lane & 7) * 8;           // s-local
                bf16x8 v = *(const bf16x8*)&Tw[srow * 72 + col];
                const int n = n_blk + n_w + jh * 32 + srow;
                const int h = n >> 6, d = n & 63;
                *(bf16x8*)&out[(((size_t)(bb * NHEADS + h)) * HD + d) * SEQ + s0 + col] = v;
            }
        }
    }
}

// ---------------------------------------------------------------------------
// Kernel 2: flash attention. 4 waves, 16 q/wave, kv tile 64, LDS K/V^T tiles.
// Software-pipelined: next tile's global loads issued before current compute.
// Static-shift softmax, raw v_exp_f32, register-PV via K=16 MFMA.
// ---------------------------------------------------------------------------
__global__ __launch_bounds__(256, 4) void attn_kernel(
    const bf16_t* __restrict__ Q, const bf16_t* __restrict__ K,
    const bf16_t* __restrict__ Vt, const int* __restrict__ mask,
    bf16_t* __restrict__ ctx)
{
    const int B   = blockIdx.x;            // 0..1023
    const int xcd = B & 7;
    const int idx = B >> 3;                // 0..127
    const int bh  = xcd * 4 + (idx & 3);
    const int q0  = (idx >> 2) * 64;       // block q base
    const int b   = bh >> 4;
    const int h   = bh & 15;
    const int tid  = threadIdx.x;
    const int wave = tid >> 6;
    const int lane = tid & 63;
    const int l16  = lane & 15;
    const int quad = lane >> 4;

    const bf16_t* Qh = Q  + (size_t)bh * SEQ * HD;
    const bf16_t* Kh = K  + (size_t)bh * SEQ * HD;
    const bf16_t* Vh = Vt + (size_t)bh * HD * SEQ;    // [d][s]
    const int*    mk = mask + b * SEQ;

    __shared__ __align__(16) bf16_t Ks[64 * 72];      // K tile [kv][d]; epilogue scratch
    __shared__ __align__(16) bf16_t Vs[64 * 72];      // V^T tile [d][kv]
    __shared__ __align__(16) float  bias2[SEQ];       // (mask? 0 : -1e30) - 26

    for (int i = tid; i < SEQ; i += 256)
        bias2[i] = (mk[i] ? 0.0f : -1.0e30f) - SHIFT2;

    const int qw = q0 + wave * 16;

    bf16x8 bQ[2];
#pragma unroll
    for (int kc = 0; kc < 2; kc++)
        bQ[kc] = ldg8(Qh + (size_t)(qw + l16) * HD + kc * 32 + quad * 8);

    floatx4 O[4];
    floatx4 psum = (floatx4)0.0f;
#pragma unroll
    for (int dt = 0; dt < 4; dt++) O[dt] = (floatx4)0.0f;

    const int r0 = tid >> 3;               // 0..31
    const int c0 = (tid & 7) * 8;          // 0..56

    // preload tile 0
    bf16x8 k0v = ldg8(Kh + (size_t)(r0)      * HD + c0);
    bf16x8 k1v = ldg8(Kh + (size_t)(32 + r0) * HD + c0);
    bf16x8 v0v = ldg8(Vh + (size_t)(r0)      * SEQ + c0);
    bf16x8 v1v = ldg8(Vh + (size_t)(32 + r0) * SEQ + c0);

    for (int kt = 0; kt < SEQ; kt += 64) {
        __syncthreads();                   // WAR (covers bias2 on iter 0)
        *(bf16x8*)&Ks[r0 * 72 + c0]        = k0v;
        *(bf16x8*)&Ks[(32 + r0) * 72 + c0] = k1v;
        *(bf16x8*)&Vs[r0 * 72 + c0]        = v0v;
        *(bf16x8*)&Vs[(32 + r0) * 72 + c0] = v1v;
        __syncthreads();                   // RAW

        // prefetch next tile BEFORE compute (latency hidden behind compute)
        if (kt + 64 < SEQ) {
            k0v = ldg8(Kh + (size_t)(kt + 64 + r0)      * HD + c0);
            k1v = ldg8(Kh + (size_t)(kt + 96 + r0)      * HD + c0);
            v0v = ldg8(Vh + (size_t)(r0)      * SEQ + kt + 64 + c0);
            v1v = ldg8(Vh + (size_t)(32 + r0) * SEQ + kt + 64 + c0);
        }

#pragma unroll
        for (int kvt = 0; kvt < 4; kvt++) {
            floatx4 s = (floatx4)0.0f;
#pragma unroll
            for (int kc = 0; kc < 2; kc++) {
                bf16x8 aK = *(const bf16x8*)&Ks[(kvt * 16 + l16) * 72 + kc * 32 + quad * 8];
                s = mfma16(aK, bQ[kc], s);
            }
            const floatx4 ad = *(const floatx4*)&bias2[kt + kvt * 16 + quad * 4];
            floatx4 p;
#pragma unroll
            for (int r = 0; r < 4; r++)
                p[r] = __builtin_amdgcn_exp2f(fmaf(s[r], L2E, ad[r]));  // raw v_exp_f32
            psum += p;
            bf16x4 pb;
#pragma unroll
            for (int r = 0; r < 4; r++) pb[r] = (bf16_t)p[r];
            // PV directly from registers: S^T C-layout == K=16 MFMA B-layout
#pragma unroll
            for (int dt = 0; dt < 4; dt++) {
                bf16x4 aV = *(const bf16x4*)&Vs[(dt * 16 + l16) * 72 + kvt * 16 + quad * 4];
                O[dt] = mfma16k16(aV, pb, O[dt]);
            }
        }
    }

    float su = psum[0] + psum[1] + psum[2] + psum[3];
    su += __shfl_xor(su, 16, 64);
    su += __shfl_xor(su, 32, 64);
    const float linv = (su > 0.0f) ? 1.0f / su : 0.0f;

    __syncthreads();                       // loop reads done; Ks reusable
    bf16_t* Pw = Ks + wave * 1152;         // per-wave 16x72 scratch
#pragma unroll
    for (int dt = 0; dt < 4; dt++) {
        floatx4 o = O[dt] * linv;
        bf16x4 pk;
#pragma unroll
        for (int r = 0; r < 4; r++) pk[r] = (bf16_t)o[r];
        *(bf16x4*)&Pw[l16 * 72 + dt * 16 + quad * 4] = pk;
    }
#pragma unroll
    for (int ch = 0; ch < 2; ch++) {
        const int cc  = ch * 64 + lane;
        const int row = cc >> 3;
        const int col = (cc & 7) * 8;
        bf16x8 vv = *(const bf16x8*)&Pw[row * 72 + col];
        *(bf16x8*)&ctx[((size_t)(b * SEQ + qw + row)) * HID + h * 64 + col] = vv;
    }
}

// ---------------------------------------------------------------------------
// Kernel 3: res = ctx @ Wo^T + bo (residual in ln). 64x128 tile, 512 blocks.
// Wave w computes 64m x 32n (n_w = w*32): 4x2 MFMA frags.
// ---------------------------------------------------------------------------
__global__ __launch_bounds__(256) void oproj_kernel(
    const bf16_t* __restrict__ C, const bf16_t* __restrict__ Wo,
    const float* __restrict__ bo, float* __restrict__ res)
{
    const int tid  = threadIdx.x;
    const int lane = tid & 63;
    const int wave = tid >> 6;
    const int l16  = lane & 15;
    const int quad = lane >> 4;
    const int m_blk = blockIdx.y * 64;
    const int n_blk = blockIdx.x * 128;
    const int n_w   = wave * 32;

    // union: staging (A 4096 + B 8192 B) / fp32 transpose (4 x 2304 B)
    __shared__ __align__(16) char smem[12288];
    bf16_t* As = (bf16_t*)smem;
    bf16_t* Bs = (bf16_t*)(smem + 4096);

    floatx4 acc[4][2];
#pragma unroll
    for (int i = 0; i < 4; i++)
#pragma unroll
        for (int j = 0; j < 2; j++) acc[i][j] = (floatx4)0.0f;

    for (int k0 = 0; k0 < HID; k0 += 32) {
        __syncthreads();
        stage64x32 (C  + (size_t)m_blk * HID, HID, k0, As, wave, lane);
        stage128x32(Wo + (size_t)n_blk * HID, HID, k0, Bs, wave, lane);
        __syncthreads();

        bf16x8 a[4], b[2];
#pragma unroll
        for (int i = 0; i < 4; i++) a[i] = *(const bf16x8*)&As[(i * 16 + l16) * 32 + quad * 8];
#pragma unroll
        for (int j = 0; j < 2; j++) b[j] = *(const bf16x8*)&Bs[(n_w + j * 16 + l16) * 32 + quad * 8];
#pragma unroll
        for (int i = 0; i < 4; i++)
#pragma unroll
            for (int j = 0; j < 2; j++) acc[i][j] = mfma16(a[i], b[j], acc[i][j]);
    }
    __syncthreads();                                       // smem reusable

    float bv_[2];
#pragma unroll
    for (int j = 0; j < 2; j++) bv_[j] = bo[n_blk + n_w + j * 16 + l16];

    float* Tw = (float*)(smem + wave * 2304);              // 16 x 36 fp32
#pragma unroll
    for (int ch = 0; ch < 4; ch++) {
#pragma unroll
        for (int j = 0; j < 2; j++)
#pragma unroll
            for (int r = 0; r < 4; r++)
                Tw[(quad * 4 + r) * 36 + j * 16 + l16] = acc[ch][j][r] + bv_[j];
        // 16 rows x 32 cols = 128 float4 = 2 per lane
#pragma unroll
        for (int cc = 0; cc < 2; cc++) {
            const int idx = cc * 64 + lane;                // 0..127
            const int row = idx >> 3;                      // 0..15
            const int col = (idx & 7) * 4;                 // 0..28
            float4 v = *(const float4*)&Tw[row * 36 + col];
            const int m = m_blk + ch * 16 + row;
            *(float4*)&res[(size_t)m * HID + n_blk + n_w + col] = v;
        }
    }
}

// ---------------------------------------------------------------------------
// Kernel 4: LayerNorm((res + X)) over rows of 1024 -> fp32 out
// ---------------------------------------------------------------------------
__global__ __launch_bounds__(256) void ln_kernel(
    const float* __restrict__ res, const float* __restrict__ X,
    const float* __restrict__ g, const float* __restrict__ be,
    float* __restrict__ out)
{
    __shared__ float red1[4], red2[4];
    const int row  = blockIdx.x;
    const int lane = threadIdx.x & 63;
    const int wave = threadIdx.x >> 6;
    const float4 a = ((const float4*)(res + (size_t)row * HID))[threadIdx.x];
    const float4 x = ((const float4*)(X   + (size_t)row * HID))[threadIdx.x];
    float4 v;
    v.x = a.x + x.x; v.y = a.y + x.y; v.z = a.z + x.z; v.w = a.w + x.w;

    float s = v.x + v.y + v.z + v.w;
#pragma unroll
    for (int off = 1; off < 64; off <<= 1) s += __shfl_xor(s, off, 64);
    if (lane == 0) red1[wave] = s;
    __syncthreads();
    const float mu = (red1[0] + red1[1] + red1[2] + red1[3]) * (1.0f / HID);

    const float d0 = v.x - mu, d1 = v.y - mu, d2 = v.z - mu, d3 = v.w - mu;
    float ss = d0 * d0 + d1 * d1 + d2 * d2 + d3 * d3;
#pragma unroll
    for (int off = 1; off < 64; off <<= 1) ss += __shfl_xor(ss, off, 64);
    if (lane == 0) red2[wave] = ss;
    __syncthreads();
    const float var = (red2[0] + red2[1] + red2[2] + red2[3]) * (1.0f / HID);
    const float rstd = rsqrtf(var + LNEPS);

    const float4 gv = ((const float4*)g)[threadIdx.x];
    const float4 bv = ((const float4*)be)[threadIdx.x];
    float4 o;
    o.x = d0 * rstd * gv.x + bv.x;
    o.y = d1 * rstd * gv.y + bv.y;
    o.z = d2 * rstd * gv.z + bv.z;
    o.w = d3 * rstd * gv.w + bv.w;
    ((float4*)(out + (size_t)row * HID))[threadIdx.x] = o;
}

// ---------------------------------------------------------------------------
extern "C" void kernel_launch(void* const* d_in, const int* in_sizes, int n_in,
                              void* d_out, int out_size, void* d_ws, size_t ws_size,
                              hipStream_t stream)
{
    const float* X  = (const float*)d_in[0];
    const int* mask = (const int*)d_in[1];
    const float* Wq = (const float*)d_in[2];  const float* bq = (const float*)d_in[3];
    const float* Wk = (const float*)d_in[4];  const float* bk = (const float*)d_in[5];
    const float* Wv = (const float*)d_in[6];  const float* bv = (const float*)d_in[7];
    const float* Wo = (const float*)d_in[8];  const float* bo = (const float*)d_in[9];
    const float* g  = (const float*)d_in[10]; const float* be = (const float*)d_in[11];
    float* out = (float*)d_out;

    char* ws = (char*)d_ws;
    bf16_t* Qb  = (bf16_t*)(ws);                          // [0, 8M)
    bf16_t* Kb  = (bf16_t*)(ws + (8ull  << 20));          // [8M, 16M)
    bf16_t* Vb  = (bf16_t*)(ws + (16ull << 20));          // [16M, 24M)  V^T [bh][d][s]
    bf16_t* Cb  = (bf16_t*)(ws + (24ull << 20));          // [24M, 32M)
    float*  Rb  = (float*)(ws);                           // [0, 16M) aliases dead Q/K
    bf16_t* Xc  = (bf16_t*)(ws + (32ull << 20));          // [32M, 40M)
    bf16_t* Wqc = (bf16_t*)(ws + (40ull << 20));
    bf16_t* Wkc = (bf16_t*)(ws + (42ull << 20));
    bf16_t* Wvc = (bf16_t*)(ws + (44ull << 20));
    bf16_t* Woc = (bf16_t*)(ws + (46ull << 20));

    cvt_kernel <<<dim3(128, 1, 5), 256, 0, stream>>>(X, Wq, Wk, Wv, Wo, Xc, Wqc, Wkc, Wvc, Woc);
    qkv_kernel <<<dim3(8, 32, 3), 256, 0, stream>>>(Xc, Wqc, bq, Wkc, bk, Wvc, bv, Qb, Kb, Vb);
    attn_kernel<<<dim3(32 * 32), 256, 0, stream>>>(Qb, Kb, Vb, mask, Cb);
    oproj_kernel<<<dim3(8, 64), 256, 0, stream>>>(Cb, Woc, bo, Rb);
    ln_kernel  <<<MTOT, 256, 0, stream>>>(Rb, X, g, be, out);
}